// Round 1
// baseline (356.905 us; speedup 1.0000x reference)
//
#include <hip/hip_runtime.h>

#define BATCH 16
#define HH 512
#define WW 512
#define NPIX (BATCH * HH * WW)

#define TW 32
#define TH 8
#define RAD 4
#define LW (TW + 2 * RAD)   // 40
#define LH (TH + 2 * RAD)   // 16

// ---------------------------------------------------------------------------
// Kernel 0: normalize the 9x9 filter: f = (filt + 10) / sum(filt + 10)
// ---------------------------------------------------------------------------
__global__ void norm_filter_kernel(const float* __restrict__ filt,
                                   float* __restrict__ f) {
    __shared__ float sh[128];
    int tid = threadIdx.x;
    float v = (tid < 81) ? (filt[tid] + 10.0f) : 0.0f;
    sh[tid] = v;
    __syncthreads();
    for (int o = 64; o > 0; o >>= 1) {
        if (tid < o) sh[tid] += sh[tid + o];
        __syncthreads();
    }
    float sum = sh[0];
    if (tid < 81) f[tid] = v / sum;
}

// ---------------------------------------------------------------------------
// Kernel 1: fused channel-sum + conv -> local mean m, and t = sum_c (x_c-m)^2
// One block computes a 32x8 output tile; halo of 4 each side, zero-padded.
// ---------------------------------------------------------------------------
__global__ __launch_bounds__(256) void conv_mean_kernel(
        const float* __restrict__ x, const float* __restrict__ f,
        float* __restrict__ m, float* __restrict__ t) {
    __shared__ float tile[LH][LW];
    __shared__ float fs[81];

    const int tx = threadIdx.x, ty = threadIdx.y;
    const int tid = ty * TW + tx;
    const int b = blockIdx.z;
    const int h0 = blockIdx.y * TH;
    const int w0 = blockIdx.x * TW;
    const float* xb = x + (size_t)b * HH * WW * 3;

    // cooperative halo load: channel-sum of x, zero outside the image (SAME pad)
    for (int i = tid; i < LH * LW; i += 256) {
        int r = i / LW, c = i % LW;
        int gh = h0 - RAD + r, gw = w0 - RAD + c;
        float v = 0.0f;
        if (gh >= 0 && gh < HH && gw >= 0 && gw < WW) {
            const float* xp = xb + ((size_t)gh * WW + gw) * 3;
            v = xp[0] + xp[1] + xp[2];
        }
        tile[r][c] = v;
    }
    if (tid < 81) fs[tid] = f[tid];
    __syncthreads();

    float acc = 0.0f;
#pragma unroll
    for (int dh = 0; dh < 9; dh++) {
#pragma unroll
        for (int dw = 0; dw < 9; dw++) {
            acc += tile[ty + dh][tx + dw] * fs[dh * 9 + dw];
        }
    }

    const int h = h0 + ty, w = w0 + tx;
    const size_t idx = ((size_t)b * HH + h) * WW + w;
    m[idx] = acc;

    const float* xp = xb + ((size_t)h * WW + w) * 3;
    float d0 = xp[0] - acc;
    float d1 = xp[1] - acc;
    float d2 = xp[2] - acc;
    t[idx] = d0 * d0 + d1 * d1 + d2 * d2;
}

// ---------------------------------------------------------------------------
// Kernel 2: conv(t, f) -> sigma = sqrt(.), plus per-batch sum of sigma
// ---------------------------------------------------------------------------
__global__ __launch_bounds__(256) void conv_sigma_kernel(
        const float* __restrict__ t, const float* __restrict__ f,
        float* __restrict__ sig, float* __restrict__ bsum) {
    __shared__ float tile[LH][LW];
    __shared__ float fs[81];
    __shared__ float wsum[4];

    const int tx = threadIdx.x, ty = threadIdx.y;
    const int tid = ty * TW + tx;
    const int b = blockIdx.z;
    const int h0 = blockIdx.y * TH;
    const int w0 = blockIdx.x * TW;
    const float* tb = t + (size_t)b * HH * WW;

    for (int i = tid; i < LH * LW; i += 256) {
        int r = i / LW, c = i % LW;
        int gh = h0 - RAD + r, gw = w0 - RAD + c;
        float v = 0.0f;
        if (gh >= 0 && gh < HH && gw >= 0 && gw < WW) {
            v = tb[(size_t)gh * WW + gw];
        }
        tile[r][c] = v;
    }
    if (tid < 81) fs[tid] = f[tid];
    __syncthreads();

    float acc = 0.0f;
#pragma unroll
    for (int dh = 0; dh < 9; dh++) {
#pragma unroll
        for (int dw = 0; dw < 9; dw++) {
            acc += tile[ty + dh][tx + dw] * fs[dh * 9 + dw];
        }
    }

    float sg = sqrtf(fmaxf(acc, 0.0f));
    const int h = h0 + ty, w = w0 + tx;
    const size_t idx = ((size_t)b * HH + h) * WW + w;
    sig[idx] = sg;

    // block reduction of sigma for the batch mean
    float v = sg;
#pragma unroll
    for (int o = 32; o > 0; o >>= 1) v += __shfl_down(v, o);
    if ((tid & 63) == 0) wsum[tid >> 6] = v;
    __syncthreads();
    if (tid == 0) atomicAdd(&bsum[b], wsum[0] + wsum[1] + wsum[2] + wsum[3]);
}

// ---------------------------------------------------------------------------
// Kernel 3: out = (x - m) / max(mean_b, sigma); 4 pixels (12 floats) / thread
// ---------------------------------------------------------------------------
__global__ __launch_bounds__(256) void final_kernel(
        const float* __restrict__ x, const float* __restrict__ m,
        const float* __restrict__ sig, const float* __restrict__ bsum,
        float* __restrict__ out) {
    const int i = blockIdx.x * 256 + threadIdx.x;   // group of 4 pixels
    const int b = i >> 16;                          // (i*4) / (512*512)
    const float mean = bsum[b] * (1.0f / (HH * WW));

    float4 mv = ((const float4*)m)[i];
    float4 sv = ((const float4*)sig)[i];
    const float4* xp = (const float4*)x + (size_t)i * 3;
    float4 a = xp[0], bb = xp[1], cc = xp[2];

    float d0 = fmaxf(mean, sv.x);
    float d1 = fmaxf(mean, sv.y);
    float d2 = fmaxf(mean, sv.z);
    float d3 = fmaxf(mean, sv.w);

    float4 o0, o1, o2;
    o0.x = (a.x - mv.x) / d0;
    o0.y = (a.y - mv.x) / d0;
    o0.z = (a.z - mv.x) / d0;
    o0.w = (a.w - mv.y) / d1;
    o1.x = (bb.x - mv.y) / d1;
    o1.y = (bb.y - mv.y) / d1;
    o1.z = (bb.z - mv.z) / d2;
    o1.w = (bb.w - mv.z) / d2;
    o2.x = (cc.x - mv.z) / d2;
    o2.y = (cc.y - mv.w) / d3;
    o2.z = (cc.z - mv.w) / d3;
    o2.w = (cc.w - mv.w) / d3;

    float4* op = (float4*)out + (size_t)i * 3;
    op[0] = o0;
    op[1] = o1;
    op[2] = o2;
}

// ---------------------------------------------------------------------------
extern "C" void kernel_launch(void* const* d_in, const int* in_sizes, int n_in,
                              void* d_out, int out_size, void* d_ws, size_t ws_size,
                              hipStream_t stream) {
    const float* x = (const float*)d_in[0];
    const float* filt = (const float*)d_in[1];
    float* out = (float*)d_out;

    char* ws = (char*)d_ws;
    float* f = (float*)ws;                       // 81 floats
    float* bsum = (float*)(ws + 1024);           // BATCH floats
    float* m = (float*)(ws + 8192);              // NPIX floats (16 MiB)
    float* t = m + NPIX;                         // NPIX floats
    float* sig = t + NPIX;                       // NPIX floats

    // zero the per-batch sigma accumulators (ws is poisoned 0xAA each call)
    hipMemsetAsync(bsum, 0, BATCH * sizeof(float), stream);

    norm_filter_kernel<<<1, 128, 0, stream>>>(filt, f);

    dim3 cblock(TW, TH);
    dim3 cgrid(WW / TW, HH / TH, BATCH);
    conv_mean_kernel<<<cgrid, cblock, 0, stream>>>(x, f, m, t);
    conv_sigma_kernel<<<cgrid, cblock, 0, stream>>>(t, f, sig, bsum);

    final_kernel<<<NPIX / 4 / 256, 256, 0, stream>>>(x, m, sig, bsum, out);
}

// Round 3
// 154.905 us; speedup vs baseline: 2.3040x; 2.3040x over previous
//
#include <hip/hip_runtime.h>

#define BATCH 16
#define HH 512
#define WW 512
#define NPIX (BATCH * HH * WW)

#define TW 32          // threads x = output tile width
#define TH 8           // threads y
#define ROWS 4         // output rows per thread
#define OTH (TH*ROWS)  // 32 = output tile height
#define RAD 4
#define LW (TW + 2 * RAD)   // 40
#define LH (OTH + 2 * RAD)  // 40

// ---------------------------------------------------------------------------
// Kernel 0: normalize the 9x9 filter: f = (filt + 10) / sum(filt + 10)
// ---------------------------------------------------------------------------
__global__ void norm_filter_kernel(const float* __restrict__ filt,
                                   float* __restrict__ f) {
    __shared__ float sh[128];
    int tid = threadIdx.x;
    float v = (tid < 81) ? (filt[tid] + 10.0f) : 0.0f;
    sh[tid] = v;
    __syncthreads();
    for (int o = 64; o > 0; o >>= 1) {
        if (tid < o) sh[tid] += sh[tid + o];
        __syncthreads();
    }
    float sum = sh[0];
    if (tid < 81) f[tid] = v / sum;
}

// ---------------------------------------------------------------------------
// Kernel 1: fused channel-sum + conv -> local mean m, and t = sum_c (x_c-m)^2
// 32x32 output tile / block; each thread computes 4 consecutive rows via a
// sliding 12-row window (27 LDS reads per output instead of 81).
// ---------------------------------------------------------------------------
__global__ __launch_bounds__(256) void conv_mean_kernel(
        const float* __restrict__ x, const float* __restrict__ f,
        float* __restrict__ m, float* __restrict__ t) {
    __shared__ float tile[LH][LW];
    __shared__ float fs[81];

    const int tx = threadIdx.x, ty = threadIdx.y;
    const int tid = ty * TW + tx;
    const int b = blockIdx.z;
    const int h0 = blockIdx.y * OTH;
    const int w0 = blockIdx.x * TW;
    const float* xb = x + (size_t)b * HH * WW * 3;

    // cooperative halo load: channel-sum of x, zero outside (SAME padding)
    for (int i = tid; i < LH * LW; i += 256) {
        int r = i / LW, c = i - r * LW;
        int gh = h0 - RAD + r, gw = w0 - RAD + c;
        float v = 0.0f;
        if (gh >= 0 && gh < HH && gw >= 0 && gw < WW) {
            const float* xp = xb + ((size_t)gh * WW + gw) * 3;
            v = xp[0] + xp[1] + xp[2];
        }
        tile[r][c] = v;
    }
    if (tid < 81) fs[tid] = f[tid];
    __syncthreads();

    const int r0 = ty * ROWS;
    float acc[ROWS] = {0.f, 0.f, 0.f, 0.f};
#pragma unroll
    for (int tr = 0; tr < ROWS + 8; tr++) {
        float v[9];
#pragma unroll
        for (int j = 0; j < 9; j++) v[j] = tile[r0 + tr][tx + j];
#pragma unroll
        for (int o = 0; o < ROWS; o++) {
            const int dh = tr - o;
            if (dh >= 0 && dh < 9) {
#pragma unroll
                for (int j = 0; j < 9; j++) acc[o] += v[j] * fs[dh * 9 + j];
            }
        }
    }

#pragma unroll
    for (int o = 0; o < ROWS; o++) {
        const int h = h0 + r0 + o, w = w0 + tx;
        const size_t idx = ((size_t)b * HH + h) * WW + w;
        m[idx] = acc[o];
        const float* xp = xb + ((size_t)h * WW + w) * 3;
        float d0 = xp[0] - acc[o];
        float d1 = xp[1] - acc[o];
        float d2 = xp[2] - acc[o];
        t[idx] = d0 * d0 + d1 * d1 + d2 * d2;
    }
}

// ---------------------------------------------------------------------------
// Kernel 2: conv(t, f) -> sigma = sqrt(.), per-block partial sums (NO atomics)
// ---------------------------------------------------------------------------
__global__ __launch_bounds__(256) void conv_sigma_kernel(
        const float* __restrict__ t, const float* __restrict__ f,
        float* __restrict__ sig, float* __restrict__ partial) {
    __shared__ float tile[LH][LW];
    __shared__ float fs[81];
    __shared__ float wsum[4];

    const int tx = threadIdx.x, ty = threadIdx.y;
    const int tid = ty * TW + tx;
    const int b = blockIdx.z;
    const int h0 = blockIdx.y * OTH;
    const int w0 = blockIdx.x * TW;
    const float* tb = t + (size_t)b * HH * WW;

    for (int i = tid; i < LH * LW; i += 256) {
        int r = i / LW, c = i - r * LW;
        int gh = h0 - RAD + r, gw = w0 - RAD + c;
        float v = 0.0f;
        if (gh >= 0 && gh < HH && gw >= 0 && gw < WW) {
            v = tb[(size_t)gh * WW + gw];
        }
        tile[r][c] = v;
    }
    if (tid < 81) fs[tid] = f[tid];
    __syncthreads();

    const int r0 = ty * ROWS;
    float acc[ROWS] = {0.f, 0.f, 0.f, 0.f};
#pragma unroll
    for (int tr = 0; tr < ROWS + 8; tr++) {
        float v[9];
#pragma unroll
        for (int j = 0; j < 9; j++) v[j] = tile[r0 + tr][tx + j];
#pragma unroll
        for (int o = 0; o < ROWS; o++) {
            const int dh = tr - o;
            if (dh >= 0 && dh < 9) {
#pragma unroll
                for (int j = 0; j < 9; j++) acc[o] += v[j] * fs[dh * 9 + j];
            }
        }
    }

    float psum = 0.0f;
#pragma unroll
    for (int o = 0; o < ROWS; o++) {
        float sg = sqrtf(fmaxf(acc[o], 0.0f));
        const int h = h0 + r0 + o, w = w0 + tx;
        sig[((size_t)b * HH + h) * WW + w] = sg;
        psum += sg;
    }

    // block reduction -> one private partial slot per block (no contention)
#pragma unroll
    for (int o = 32; o > 0; o >>= 1) psum += __shfl_down(psum, o);
    if ((tid & 63) == 0) wsum[tid >> 6] = psum;
    __syncthreads();
    if (tid == 0)
        partial[b * 256 + blockIdx.y * 16 + blockIdx.x] =
            wsum[0] + wsum[1] + wsum[2] + wsum[3];
}

// ---------------------------------------------------------------------------
// Kernel 2.5: reduce 256 partials per batch -> bsum[b]
// ---------------------------------------------------------------------------
__global__ __launch_bounds__(256) void reduce_bsum_kernel(
        const float* __restrict__ partial, float* __restrict__ bsum) {
    __shared__ float wsum[4];
    const int b = blockIdx.x, tid = threadIdx.x;
    float v = partial[b * 256 + tid];
#pragma unroll
    for (int o = 32; o > 0; o >>= 1) v += __shfl_down(v, o);
    if ((tid & 63) == 0) wsum[tid >> 6] = v;
    __syncthreads();
    if (tid == 0) bsum[b] = wsum[0] + wsum[1] + wsum[2] + wsum[3];
}

// ---------------------------------------------------------------------------
// Kernel 3: out = (x - m) / max(mean_b, sigma); 4 pixels (12 floats) / thread
// ---------------------------------------------------------------------------
__global__ __launch_bounds__(256) void final_kernel(
        const float* __restrict__ x, const float* __restrict__ m,
        const float* __restrict__ sig, const float* __restrict__ bsum,
        float* __restrict__ out) {
    const int i = blockIdx.x * 256 + threadIdx.x;   // group of 4 pixels
    const int b = i >> 16;                          // (i*4) / (512*512)
    const float mean = bsum[b] * (1.0f / (HH * WW));

    float4 mv = ((const float4*)m)[i];
    float4 sv = ((const float4*)sig)[i];
    const float4* xp = (const float4*)x + (size_t)i * 3;
    float4 a = xp[0], bb = xp[1], cc = xp[2];

    float d0 = fmaxf(mean, sv.x);
    float d1 = fmaxf(mean, sv.y);
    float d2 = fmaxf(mean, sv.z);
    float d3 = fmaxf(mean, sv.w);

    float4 o0, o1, o2;
    o0.x = (a.x - mv.x) / d0;
    o0.y = (a.y - mv.x) / d0;
    o0.z = (a.z - mv.x) / d0;
    o0.w = (a.w - mv.y) / d1;
    o1.x = (bb.x - mv.y) / d1;
    o1.y = (bb.y - mv.y) / d1;
    o1.z = (bb.z - mv.z) / d2;
    o1.w = (bb.w - mv.z) / d2;
    o2.x = (cc.x - mv.z) / d2;
    o2.y = (cc.y - mv.w) / d3;
    o2.z = (cc.z - mv.w) / d3;
    o2.w = (cc.w - mv.w) / d3;

    float4* op = (float4*)out + (size_t)i * 3;
    op[0] = o0;
    op[1] = o1;
    op[2] = o2;
}

// ---------------------------------------------------------------------------
extern "C" void kernel_launch(void* const* d_in, const int* in_sizes, int n_in,
                              void* d_out, int out_size, void* d_ws, size_t ws_size,
                              hipStream_t stream) {
    const float* x = (const float*)d_in[0];
    const float* filt = (const float*)d_in[1];
    float* out = (float*)d_out;

    char* ws = (char*)d_ws;
    float* f = (float*)ws;                          // 81 floats
    float* bsum = (float*)(ws + 512);               // 16 floats
    float* partial = (float*)(ws + 1024);           // 4096 floats (16 KB)
    float* m = (float*)(ws + 32768);                // NPIX floats (16.8 MB)
    float* t = m + NPIX;                            // NPIX floats
    float* sig = t + NPIX;                          // NPIX floats

    norm_filter_kernel<<<1, 128, 0, stream>>>(filt, f);

    dim3 cblock(TW, TH);
    dim3 cgrid(WW / TW, HH / OTH, BATCH);           // (16, 16, 16)
    conv_mean_kernel<<<cgrid, cblock, 0, stream>>>(x, f, m, t);
    conv_sigma_kernel<<<cgrid, cblock, 0, stream>>>(t, f, sig, partial);
    reduce_bsum_kernel<<<BATCH, 256, 0, stream>>>(partial, bsum);

    final_kernel<<<NPIX / 4 / 256, 256, 0, stream>>>(x, m, sig, bsum, out);
}